// Round 1
// baseline (64.910 us; speedup 1.0000x reference)
//
#include <hip/hip_runtime.h>

constexpr int SEQ_LEN = 200;
constexpr int BATCH   = 4096;
constexpr int V       = 50000;
constexpr int V_WORDS = (V + 31) / 32;   // 1563 words = 6252 B LDS bitmap

__global__ __launch_bounds__(256) void MNB_8151847928093_kernel(
    const int*   __restrict__ text,   // [SEQ_LEN, BATCH] row-major
    const float* __restrict__ W,      // [V]
    const float* __restrict__ bias,   // [1]
    float*       __restrict__ out)    // [BATCH]
{
    __shared__ unsigned int bitmap[V_WORDS];
    __shared__ float partial[4];

    const int b   = blockIdx.x;
    const int tid = threadIdx.x;

    // zero the presence bitmap (1563 words / 256 threads = 7 iters)
    for (int i = tid; i < V_WORDS; i += 256) bitmap[i] = 0u;
    __syncthreads();

    float sum = 0.0f;
    if (tid < SEQ_LEN) {
        const int tok = text[tid * BATCH + b];
        const unsigned int m   = 1u << (tok & 31);
        const unsigned int old = atomicOr(&bitmap[tok >> 5], m);
        if (!(old & m)) sum = W[tok];   // first setter owns this token
    }

    // wave (64-lane) shuffle reduction
    #pragma unroll
    for (int off = 32; off > 0; off >>= 1)
        sum += __shfl_down(sum, off, 64);

    const int wave = tid >> 6;
    const int lane = tid & 63;
    if (lane == 0) partial[wave] = sum;
    __syncthreads();

    if (tid == 0)
        out[b] = partial[0] + partial[1] + partial[2] + partial[3] + bias[0];
}

extern "C" void kernel_launch(void* const* d_in, const int* in_sizes, int n_in,
                              void* d_out, int out_size, void* d_ws, size_t ws_size,
                              hipStream_t stream) {
    const int*   text = (const int*)d_in[0];
    const float* W    = (const float*)d_in[1];
    const float* bias = (const float*)d_in[2];
    float*       out  = (float*)d_out;

    MNB_8151847928093_kernel<<<BATCH, 256, 0, stream>>>(text, W, bias, out);
}